// Round 13
// baseline (235.675 us; speedup 1.0000x reference)
//
#include <hip/hip_runtime.h>
#include <hip/hip_bf16.h>

// Problem: x [B,U,C] fp32, W [1,C,J,S,U] fp32, out [B,J,S,1] fp32.
// passA: LDS-staged blocked bf16 MFMA GEMM s = xA · (cc*Wn)^T, cc fused into
//        the B-staging. Block tile 128x128x256, 8 waves, 64 K-slices.
// passB: bf16 MFMA GEMM G[u][n][c] = sum_b vB[n][b] xB[u][c][b] with the
//        W∘G contraction fused in the epilogue; atomicAdd into bb[j][c].
#define BB 128
#define UU 8
#define CC 2048
#define JJ 32
#define SS 16

typedef unsigned int u32;
typedef unsigned short u16;
typedef __attribute__((ext_vector_type(8))) short bf16x8;
typedef __attribute__((ext_vector_type(4))) float f32x4;

__device__ __forceinline__ float bflo(u32 p) { return __uint_as_float(p << 16); }
__device__ __forceinline__ float bfhi(u32 p) { return __uint_as_float(p & 0xffff0000u); }
__device__ __forceinline__ u32 f2b(float f) {  // RNE fp32->bf16 bits
    u32 bits = __float_as_uint(f);
    u32 r = bits + 0x7fffu + ((bits >> 16) & 1u);
    return r >> 16;
}
__device__ __forceinline__ u32 pack2(float a, float b) { return f2b(a) | (f2b(b) << 16); }
__device__ __forceinline__ uint4 scale4(uint4 p, float cw) {
    uint4 o;
    o.x = pack2(bflo(p.x) * cw, bfhi(p.x) * cw);
    o.y = pack2(bflo(p.y) * cw, bfhi(p.y) * cw);
    o.z = pack2(bflo(p.z) * cw, bfhi(p.z) * cw);
    o.w = pack2(bflo(p.w) * cw, bfhi(p.w) * cw);
    return o;
}

// ---------------------------------------------------------------------------
// prep (one dispatch): blocks 0..1023 build xA[b][c][u] bf16 (gemmA A-operand);
// 1024..2047 build xB[u][c][b] bf16 (gemmB B-operand); 2048..2559 build
// Wn[n=(j,s)][c][u] bf16 (gemmA B-operand / gemmB epilogue W); 2560..2575
// zero bbp.
__global__ __launch_bounds__(256) void k_prep(const float* __restrict__ x,
                                              const float* __restrict__ W,
                                              u16* __restrict__ xA,
                                              u16* __restrict__ xB,
                                              u16* __restrict__ Wn,
                                              float* __restrict__ bbp) {
    __shared__ uint4 ldsu[16][129];
    int blk = blockIdx.x, t = threadIdx.x;
    if (blk < 1024) {
        int b = blk >> 3;
        int c = (blk & 7) * 256 + t;
        const float* xf = x + (size_t)b * UU * CC;
        float v[8];
#pragma unroll
        for (int u = 0; u < 8; ++u) v[u] = xf[u * CC + c];
        uint4 p;
        p.x = pack2(v[0], v[1]);
        p.y = pack2(v[2], v[3]);
        p.z = pack2(v[4], v[5]);
        p.w = pack2(v[6], v[7]);
        ((uint4*)xA)[(size_t)b * CC + c] = p;
    } else if (blk < 2048) {
        int bb2 = blk - 1024;
        int u = bb2 >> 7, c0 = (bb2 & 127) * 16;
        float* ldsf = (float*)ldsu;
        int b = t >> 1, h = t & 1;
        const float4* x4 = (const float4*)(x + ((size_t)b * UU + u) * CC + c0);
        float4 lo = x4[h * 2], hi = x4[h * 2 + 1];
        ldsf[(h * 8 + 0) * 129 + b] = lo.x; ldsf[(h * 8 + 1) * 129 + b] = lo.y;
        ldsf[(h * 8 + 2) * 129 + b] = lo.z; ldsf[(h * 8 + 3) * 129 + b] = lo.w;
        ldsf[(h * 8 + 4) * 129 + b] = hi.x; ldsf[(h * 8 + 5) * 129 + b] = hi.y;
        ldsf[(h * 8 + 6) * 129 + b] = hi.z; ldsf[(h * 8 + 7) * 129 + b] = hi.w;
        __syncthreads();
        int ci = t >> 4, k8 = t & 15;
        const float* r = ldsf + ci * 129 + k8 * 8;
        uint4 p;
        p.x = pack2(r[0], r[1]);
        p.y = pack2(r[2], r[3]);
        p.z = pack2(r[4], r[5]);
        p.w = pack2(r[6], r[7]);
        ((uint4*)xB)[((size_t)u * CC + c0 + ci) * 16 + k8] = p;
    } else if (blk < 2560) {
        int bb2 = blk - 2048;
        int ct = bb2 & 127, nt = bb2 >> 7;
        int c0 = ct * 16, n0 = nt * 128;
        const float4* Wf = (const float4*)W;
        for (int q = t; q < 2048; q += 256) {
            int ci = q >> 7, ni = q & 127;
            size_t widx = (size_t)(c0 + ci) * 512 + n0 + ni;
            float4 lo = Wf[2 * widx], hi = Wf[2 * widx + 1];
            uint4 o;
            o.x = pack2(lo.x, lo.y);
            o.y = pack2(lo.z, lo.w);
            o.z = pack2(hi.x, hi.y);
            o.w = pack2(hi.z, hi.w);
            ldsu[ci][ni] = o;
        }
        __syncthreads();
        for (int q = t; q < 2048; q += 256) {
            int ni = q >> 4, ci = q & 15;
            ((uint4*)Wn)[(size_t)(n0 + ni) * 2048 + c0 + ci] = ldsu[ci][ni];
        }
    } else {
        int base = (blk - 2560) * 4096 + t;
#pragma unroll
        for (int r = 0; r < 16; ++r) bbp[base + r * 256] = 0.f;
    }
}

// ---------------------------------------------------------------------------
// Softmax over C for each j; bbp/ccp layout [j][c].
__global__ __launch_bounds__(256) void k_softmax(const float* __restrict__ bbp,
                                                 float* __restrict__ ccp) {
    int j = blockIdx.x, t = threadIdx.x;
    __shared__ float red[4];
    __shared__ float bcast[2];
    const float* row = bbp + j * CC;
    float m = -1e30f;
    for (int c = t; c < CC; c += 256) m = fmaxf(m, row[c]);
#pragma unroll
    for (int o = 32; o > 0; o >>= 1) m = fmaxf(m, __shfl_down(m, o, 64));
    if ((t & 63) == 0) red[t >> 6] = m;
    __syncthreads();
    if (t == 0) bcast[0] = fmaxf(fmaxf(red[0], red[1]), fmaxf(red[2], red[3]));
    __syncthreads();
    float mm = bcast[0];
    float ssum = 0.f;
    for (int c = t; c < CC; c += 256) ssum += expf(row[c] - mm);
#pragma unroll
    for (int o = 32; o > 0; o >>= 1) ssum += __shfl_down(ssum, o, 64);
    if ((t & 63) == 0) red[t >> 6] = ssum;
    __syncthreads();
    if (t == 0) bcast[1] = red[0] + red[1] + red[2] + red[3];
    __syncthreads();
    float inv = 1.0f / bcast[1];
    for (int c = t; c < CC; c += 256) ccp[j * CC + c] = expf(row[c] - mm) * inv;
}

// ---------------------------------------------------------------------------
// gemmA (LDS-staged): spart[sl][b][n] = sum_{k in slice} xA[b][k] *
//   (cc[j(n),c(k)] * Wn[n][k]). Grid 256 = 64 sl x 4 nt; 512 threads (8
// waves). Block tile M128 x N128 x K256, 4 chunks of K=64 through LDS
// (row pad +1 uint4 -> uniform bank spread). Wave = 64x32 (4m x 2n tiles).
// cc applied during B-staging (bit-identical to in-loop scale4).
__global__ __launch_bounds__(512) void k_gemmA(const u16* __restrict__ xA,
                                               const u16* __restrict__ Wn,
                                               const float* __restrict__ ccp,
                                               int use_cc,
                                               float* __restrict__ spart) {
    __shared__ uint4 As[128][9];  // [m][k8]
    __shared__ uint4 Bs[128][9];  // [n][k8]
    const uint4* xA4 = (const uint4*)xA;
    const uint4* Wn4 = (const uint4*)Wn;
    int t = threadIdx.x;
    int sl = blockIdx.x >> 2;
    int n0 = (blockIdx.x & 3) * 128;
    int w = t >> 6, lane = t & 63;
    int mh = w & 1, nq = w >> 1;  // wave: m-half (64), n-quarter (32)
    int ln = lane & 15, quad = lane >> 4;
    f32x4 acc[4][2];
#pragma unroll
    for (int mt = 0; mt < 4; ++mt)
#pragma unroll
        for (int nt2 = 0; nt2 < 2; ++nt2) acc[mt][nt2] = {0.f, 0.f, 0.f, 0.f};

    for (int ch = 0; ch < 4; ++ch) {
        int cbase = sl * 32 + ch * 8;  // k8 (== c) origin of this chunk
#pragma unroll
        for (int r2 = 0; r2 < 2; ++r2) {  // stage A: 1024 uint4
            int q = t + r2 * 512;
            int row = q >> 3, k8 = q & 7;
            As[row][k8] = xA4[(size_t)row * 2048 + cbase + k8];
        }
#pragma unroll
        for (int r2 = 0; r2 < 2; ++r2) {  // stage B (+cc): 1024 uint4
            int q = t + r2 * 512;
            int ni = q >> 3, k8 = q & 7;
            uint4 wb = Wn4[(size_t)(n0 + ni) * 2048 + cbase + k8];
            if (use_cc) wb = scale4(wb, ccp[((n0 + ni) >> 4) * CC + cbase + k8]);
            Bs[ni][k8] = wb;
        }
        __syncthreads();
#pragma unroll
        for (int st = 0; st < 2; ++st) {
            bf16x8 af[4], bf[2];
#pragma unroll
            for (int mt = 0; mt < 4; ++mt)
                af[mt] = __builtin_bit_cast(bf16x8,
                         As[mh * 64 + mt * 16 + ln][st * 4 + quad]);
#pragma unroll
            for (int nt2 = 0; nt2 < 2; ++nt2)
                bf[nt2] = __builtin_bit_cast(bf16x8,
                          Bs[nq * 32 + nt2 * 16 + ln][st * 4 + quad]);
#pragma unroll
            for (int mt = 0; mt < 4; ++mt)
#pragma unroll
                for (int nt2 = 0; nt2 < 2; ++nt2)
                    acc[mt][nt2] = __builtin_amdgcn_mfma_f32_16x16x32_bf16(
                        af[mt], bf[nt2], acc[mt][nt2], 0, 0, 0);
        }
        __syncthreads();
    }
    float* outp = spart + sl * (BB * JJ * SS);
#pragma unroll
    for (int mt = 0; mt < 4; ++mt)
#pragma unroll
        for (int nt2 = 0; nt2 < 2; ++nt2)
#pragma unroll
            for (int r = 0; r < 4; ++r) {
                int b = mh * 64 + mt * 16 + quad * 4 + r;
                int n = n0 + nq * 32 + nt2 * 16 + ln;
                outp[b * 512 + n] = acc[mt][nt2][r];
            }
}

// ---------------------------------------------------------------------------
// rsq: fused 64-slice reduce + squash (norm over J, reference axis=1).
// Grid 128 (one block per b) x 512 threads (one per n). scale_pre = 1/2048
// for it0 (uniform cc folded out of the GEMM), else 1.
__global__ __launch_bounds__(512) void k_rsq(const float* __restrict__ spart,
                                             u16* __restrict__ vB,
                                             float* __restrict__ out,
                                             float scale_pre, int write_out) {
    __shared__ float s[512];
    __shared__ float sc[16];
    int b = blockIdx.x, n = threadIdx.x;
    float v = 0.f;
#pragma unroll
    for (int sl = 0; sl < 64; ++sl) v += spart[sl * (BB * JJ * SS) + b * 512 + n];
    v *= scale_pre;
    s[n] = v;
    __syncthreads();
    if (n < 16) {
        float msq = 0.f;
#pragma unroll
        for (int jj = 0; jj < 32; ++jj) {
            float tv = s[jj * 16 + n];
            msq = fmaf(tv, tv, msq);
        }
        sc[n] = msq / ((1.f + msq) * sqrtf(fmaxf(msq, 1e-30f)));
    }
    __syncthreads();
    float vv = s[n] * sc[n & 15];
    vB[n * BB + b] = (u16)f2b(vv);
    if (write_out) out[b * 512 + n] = vv;
}

// ---------------------------------------------------------------------------
// gemmBf (fused): G[u][n][c] = sum_b vB[n][b] * xB[u][c][b] computed per-wave
// in registers; epilogue multiplies by Wn[n][c][u] (wave-uniform u), reduces
// over s (in-lane r + shfl over quad), atomicAdds (1/B)*sum into bb[j][c].
// 2048 blocks x 4 waves; wave = (u, 32n x 32c tile), K=128. No LDS.
__global__ __launch_bounds__(256) void k_gemmBf(const u16* __restrict__ vB,
                                                const u16* __restrict__ xB,
                                                const u16* __restrict__ Wn,
                                                float* __restrict__ bbp) {
    const bf16x8* A8 = (const bf16x8*)vB;
    const bf16x8* B8 = (const bf16x8*)xB;
    const uint4* Wn4 = (const uint4*)Wn;
    int t = threadIdx.x;
    int w = t >> 6, lane = t & 63;
    int gw = blockIdx.x * 4 + w;  // [0,8192)
    int u = gw >> 10, rest = gw & 1023;
    int nt = rest & 15, c0 = (rest >> 4) * 32;
    int n0 = nt * 32;
    int ln = lane & 15, quad = lane >> 4;
    bf16x8 av[2][4], bx[2][4];
#pragma unroll
    for (int mt = 0; mt < 2; ++mt)
#pragma unroll
        for (int st = 0; st < 4; ++st)
            av[mt][st] = A8[(n0 + mt * 16 + ln) * 16 + quad + 4 * st];
#pragma unroll
    for (int ct = 0; ct < 2; ++ct)
#pragma unroll
        for (int st = 0; st < 4; ++st)
            bx[ct][st] = B8[((size_t)u * CC + c0 + ct * 16 + ln) * 16 + quad + 4 * st];
    f32x4 acc[2][2];
    acc[0][0] = {0.f, 0.f, 0.f, 0.f};
    acc[0][1] = acc[0][0]; acc[1][0] = acc[0][0]; acc[1][1] = acc[0][0];
#pragma unroll
    for (int st = 0; st < 4; ++st)
#pragma unroll
        for (int mt = 0; mt < 2; ++mt)
#pragma unroll
            for (int ct = 0; ct < 2; ++ct)
                acc[mt][ct] = __builtin_amdgcn_mfma_f32_16x16x32_bf16(
                    av[mt][st], bx[ct][st], acc[mt][ct], 0, 0, 0);
    // Epilogue: lane holds G[n = n0+mt*16+quad*4+r][c = c0+ct*16+ln].
#pragma unroll
    for (int mt = 0; mt < 2; ++mt) {
        int j = 2 * nt + mt;
#pragma unroll
        for (int ct = 0; ct < 2; ++ct) {
            int c = c0 + ct * 16 + ln;
            float val = 0.f;
#pragma unroll
            for (int r = 0; r < 4; ++r) {
                int n = n0 + mt * 16 + quad * 4 + r;
                uint4 wp = Wn4[(size_t)n * 2048 + c];
                u32 warr[4] = {wp.x, wp.y, wp.z, wp.w};
                u32 ww = warr[u >> 1];
                float wv = (u & 1) ? bfhi(ww) : bflo(ww);
                val = fmaf(acc[mt][ct][r], wv, val);
            }
            val += __shfl_xor(val, 16, 64);
            val += __shfl_xor(val, 32, 64);
            if (quad == 0)
                atomicAdd(&bbp[j * CC + c], val * (1.0f / BB));
        }
    }
}

// ---------------------------------------------------------------------------
extern "C" void kernel_launch(void* const* d_in, const int* in_sizes, int n_in,
                              void* d_out, int out_size, void* d_ws, size_t ws_size,
                              hipStream_t stream) {
    const float* x = (const float*)d_in[0];
    const float* W = (const float*)d_in[1];
    if (in_sizes[0] == CC * JJ * SS * UU) {  // robustness: order by size
        x = (const float*)d_in[1];
        W = (const float*)d_in[0];
    }
    float* out = (float*)d_out;  // fp32 output

    char* ws = (char*)d_ws;
    float* spart = (float*)ws;                  // 16 MiB (64 slices)
    u16* xA = (u16*)(ws + (16u << 20));         // 4 MiB
    u16* xB = (u16*)(ws + (20u << 20));         // 4 MiB
    u16* Wn = (u16*)(ws + (24u << 20));         // 16 MiB
    size_t b48 = (size_t)48u << 20;
    u16* vB = (u16*)(ws + b48);                 // 128 KiB
    float* bbp = (float*)(ws + b48 + 131072);   // 256 KiB
    float* ccp = (float*)(ws + b48 + 393216);   // 256 KiB

    k_prep<<<2576, 256, 0, stream>>>(x, W, xA, xB, Wn, bbp);

    for (int it = 0; it < 3; ++it) {
        if (it > 0) k_softmax<<<32, 256, 0, stream>>>(bbp, ccp);
        k_gemmA<<<256, 512, 0, stream>>>(xA, Wn, ccp, it > 0 ? 1 : 0, spart);
        k_rsq<<<128, 512, 0, stream>>>(spart, vB, out,
                                       it == 0 ? (1.0f / 2048.0f) : 1.0f,
                                       it == 2 ? 1 : 0);
        if (it < 2) k_gemmBf<<<2048, 256, 0, stream>>>(vB, xB, Wn, bbp);
    }
}

// Round 14
// 210.216 us; speedup vs baseline: 1.1211x; 1.1211x over previous
//
#include <hip/hip_runtime.h>
#include <hip/hip_bf16.h>

// Problem: x [B,U,C] fp32, W [1,C,J,S,U] fp32, out [B,J,S,1] fp32.
// passA: direct-load bf16 MFMA GEMM s = xA · (cc*Wn)^T, cc fused in-loop.
//        Wave tile 64x64 (4m x 4n) -> half the redundant traffic of 32x32.
// passB: bf16 MFMA GEMM G[u][n][c] = sum_b vB[n][b] xB[u][c][b] with the
//        W∘G contraction fused in the epilogue; atomicAdd into bb[j][c].
#define BB 128
#define UU 8
#define CC 2048
#define JJ 32
#define SS 16

typedef unsigned int u32;
typedef unsigned short u16;
typedef __attribute__((ext_vector_type(8))) short bf16x8;
typedef __attribute__((ext_vector_type(4))) float f32x4;

__device__ __forceinline__ float bflo(u32 p) { return __uint_as_float(p << 16); }
__device__ __forceinline__ float bfhi(u32 p) { return __uint_as_float(p & 0xffff0000u); }
__device__ __forceinline__ u32 f2b(float f) {  // RNE fp32->bf16 bits
    u32 bits = __float_as_uint(f);
    u32 r = bits + 0x7fffu + ((bits >> 16) & 1u);
    return r >> 16;
}
__device__ __forceinline__ u32 pack2(float a, float b) { return f2b(a) | (f2b(b) << 16); }
__device__ __forceinline__ uint4 scale4(uint4 p, float cw) {
    uint4 o;
    o.x = pack2(bflo(p.x) * cw, bfhi(p.x) * cw);
    o.y = pack2(bflo(p.y) * cw, bfhi(p.y) * cw);
    o.z = pack2(bflo(p.z) * cw, bfhi(p.z) * cw);
    o.w = pack2(bflo(p.w) * cw, bfhi(p.w) * cw);
    return o;
}

// ---------------------------------------------------------------------------
// prep (one dispatch): blocks 0..1023 build xA[b][c][u] bf16 (gemmA A-operand);
// 1024..2047 build xB[u][c][b] bf16 (gemmB B-operand); 2048..2559 build
// Wn[n=(j,s)][c][u] bf16 (gemmA B-operand / gemmB epilogue W); 2560..2575
// zero bbp.
__global__ __launch_bounds__(256) void k_prep(const float* __restrict__ x,
                                              const float* __restrict__ W,
                                              u16* __restrict__ xA,
                                              u16* __restrict__ xB,
                                              u16* __restrict__ Wn,
                                              float* __restrict__ bbp) {
    __shared__ uint4 ldsu[16][129];
    int blk = blockIdx.x, t = threadIdx.x;
    if (blk < 1024) {
        int b = blk >> 3;
        int c = (blk & 7) * 256 + t;
        const float* xf = x + (size_t)b * UU * CC;
        float v[8];
#pragma unroll
        for (int u = 0; u < 8; ++u) v[u] = xf[u * CC + c];
        uint4 p;
        p.x = pack2(v[0], v[1]);
        p.y = pack2(v[2], v[3]);
        p.z = pack2(v[4], v[5]);
        p.w = pack2(v[6], v[7]);
        ((uint4*)xA)[(size_t)b * CC + c] = p;
    } else if (blk < 2048) {
        int bb2 = blk - 1024;
        int u = bb2 >> 7, c0 = (bb2 & 127) * 16;
        float* ldsf = (float*)ldsu;
        int b = t >> 1, h = t & 1;
        const float4* x4 = (const float4*)(x + ((size_t)b * UU + u) * CC + c0);
        float4 lo = x4[h * 2], hi = x4[h * 2 + 1];
        ldsf[(h * 8 + 0) * 129 + b] = lo.x; ldsf[(h * 8 + 1) * 129 + b] = lo.y;
        ldsf[(h * 8 + 2) * 129 + b] = lo.z; ldsf[(h * 8 + 3) * 129 + b] = lo.w;
        ldsf[(h * 8 + 4) * 129 + b] = hi.x; ldsf[(h * 8 + 5) * 129 + b] = hi.y;
        ldsf[(h * 8 + 6) * 129 + b] = hi.z; ldsf[(h * 8 + 7) * 129 + b] = hi.w;
        __syncthreads();
        int ci = t >> 4, k8 = t & 15;
        const float* r = ldsf + ci * 129 + k8 * 8;
        uint4 p;
        p.x = pack2(r[0], r[1]);
        p.y = pack2(r[2], r[3]);
        p.z = pack2(r[4], r[5]);
        p.w = pack2(r[6], r[7]);
        ((uint4*)xB)[((size_t)u * CC + c0 + ci) * 16 + k8] = p;
    } else if (blk < 2560) {
        int bb2 = blk - 2048;
        int ct = bb2 & 127, nt = bb2 >> 7;
        int c0 = ct * 16, n0 = nt * 128;
        const float4* Wf = (const float4*)W;
        for (int q = t; q < 2048; q += 256) {
            int ci = q >> 7, ni = q & 127;
            size_t widx = (size_t)(c0 + ci) * 512 + n0 + ni;
            float4 lo = Wf[2 * widx], hi = Wf[2 * widx + 1];
            uint4 o;
            o.x = pack2(lo.x, lo.y);
            o.y = pack2(lo.z, lo.w);
            o.z = pack2(hi.x, hi.y);
            o.w = pack2(hi.z, hi.w);
            ldsu[ci][ni] = o;
        }
        __syncthreads();
        for (int q = t; q < 2048; q += 256) {
            int ni = q >> 4, ci = q & 15;
            ((uint4*)Wn)[(size_t)(n0 + ni) * 2048 + c0 + ci] = ldsu[ci][ni];
        }
    } else {
        int base = (blk - 2560) * 4096 + t;
#pragma unroll
        for (int r = 0; r < 16; ++r) bbp[base + r * 256] = 0.f;
    }
}

// ---------------------------------------------------------------------------
// Softmax over C for each j; bbp/ccp layout [j][c].
__global__ __launch_bounds__(256) void k_softmax(const float* __restrict__ bbp,
                                                 float* __restrict__ ccp) {
    int j = blockIdx.x, t = threadIdx.x;
    __shared__ float red[4];
    __shared__ float bcast[2];
    const float* row = bbp + j * CC;
    float m = -1e30f;
    for (int c = t; c < CC; c += 256) m = fmaxf(m, row[c]);
#pragma unroll
    for (int o = 32; o > 0; o >>= 1) m = fmaxf(m, __shfl_down(m, o, 64));
    if ((t & 63) == 0) red[t >> 6] = m;
    __syncthreads();
    if (t == 0) bcast[0] = fmaxf(fmaxf(red[0], red[1]), fmaxf(red[2], red[3]));
    __syncthreads();
    float mm = bcast[0];
    float ssum = 0.f;
    for (int c = t; c < CC; c += 256) ssum += expf(row[c] - mm);
#pragma unroll
    for (int o = 32; o > 0; o >>= 1) ssum += __shfl_down(ssum, o, 64);
    if ((t & 63) == 0) red[t >> 6] = ssum;
    __syncthreads();
    if (t == 0) bcast[1] = red[0] + red[1] + red[2] + red[3];
    __syncthreads();
    float inv = 1.0f / bcast[1];
    for (int c = t; c < CC; c += 256) ccp[j * CC + c] = expf(row[c] - mm) * inv;
}

// ---------------------------------------------------------------------------
// gemmA (direct-load, 64x64 wave tile): spart[sl][b][n] =
//   sum_{k in slice} xA[b][k] * (cc[j(n),c(k)] * Wn[n][k]).
// 128 K-slices (K=128 each), grid 512 x 256 thr (2048 waves, 2 blocks/CU).
// Wave = 4m x 4n tiles of 16x16x32: 8 b128 loads -> 16 MFMAs per k-step.
// use_cc=0 -> raw Wn (it0: uniform cc, 1/2048 applied in rsq).
__global__ __launch_bounds__(256) void k_gemmA(const u16* __restrict__ xA,
                                               const u16* __restrict__ Wn,
                                               const float* __restrict__ ccp,
                                               int use_cc,
                                               float* __restrict__ spart) {
    const bf16x8* A8 = (const bf16x8*)xA;
    const uint4* B4 = (const uint4*)Wn;
    int t = threadIdx.x;
    int w = t >> 6, lane = t & 63;
    int gw = blockIdx.x * 4 + w;  // [0,2048)
    int sl = gw >> 4;             // 128 slices of 16 k8
    int rest = gw & 15;
    int mg = rest & 1, ng = rest >> 1;  // 2 x 64 rows, 8 x 64 cols
    int ln = lane & 15, quad = lane >> 4;
    int rowA[4], rowB[4];
    const float* ccb[4];
#pragma unroll
    for (int mt = 0; mt < 4; ++mt) rowA[mt] = (mg * 64 + mt * 16 + ln) * 2048;
#pragma unroll
    for (int nt = 0; nt < 4; ++nt) {
        rowB[nt] = (ng * 64 + nt * 16 + ln) * 2048;
        ccb[nt] = ccp + (ng * 4 + nt) * CC;
    }
    int kk = sl * 16 + quad;
    f32x4 acc[4][4];
#pragma unroll
    for (int mt = 0; mt < 4; ++mt)
#pragma unroll
        for (int nt = 0; nt < 4; ++nt) acc[mt][nt] = {0.f, 0.f, 0.f, 0.f};
#pragma unroll
    for (int step = 0; step < 4; ++step) {
        bf16x8 a[4];
        uint4 wb[4];
#pragma unroll
        for (int mt = 0; mt < 4; ++mt) a[mt] = A8[rowA[mt] + kk];
#pragma unroll
        for (int nt = 0; nt < 4; ++nt) wb[nt] = B4[rowB[nt] + kk];
        if (use_cc) {
#pragma unroll
            for (int nt = 0; nt < 4; ++nt) wb[nt] = scale4(wb[nt], ccb[nt][kk]);
        }
        kk += 4;
#pragma unroll
        for (int mt = 0; mt < 4; ++mt)
#pragma unroll
            for (int nt = 0; nt < 4; ++nt)
                acc[mt][nt] = __builtin_amdgcn_mfma_f32_16x16x32_bf16(
                    a[mt], __builtin_bit_cast(bf16x8, wb[nt]), acc[mt][nt], 0, 0, 0);
    }
    float* outp = spart + sl * (BB * JJ * SS);
#pragma unroll
    for (int mt = 0; mt < 4; ++mt)
#pragma unroll
        for (int nt = 0; nt < 4; ++nt)
#pragma unroll
            for (int r = 0; r < 4; ++r) {
                int b = mg * 64 + mt * 16 + quad * 4 + r;
                int n = ng * 64 + nt * 16 + ln;
                outp[b * 512 + n] = acc[mt][nt][r];
            }
}

// ---------------------------------------------------------------------------
// rsq: fused 128-slice reduce + squash (norm over J, reference axis=1).
// Grid 128 (one block per b) x 512 threads (one per n). scale_pre = 1/2048
// for it0 (uniform cc folded out of the GEMM), else 1.
__global__ __launch_bounds__(512) void k_rsq(const float* __restrict__ spart,
                                             u16* __restrict__ vB,
                                             float* __restrict__ out,
                                             float scale_pre, int write_out) {
    __shared__ float s[512];
    __shared__ float sc[16];
    int b = blockIdx.x, n = threadIdx.x;
    float v = 0.f;
#pragma unroll 16
    for (int sl = 0; sl < 128; ++sl) v += spart[sl * (BB * JJ * SS) + b * 512 + n];
    v *= scale_pre;
    s[n] = v;
    __syncthreads();
    if (n < 16) {
        float msq = 0.f;
#pragma unroll
        for (int jj = 0; jj < 32; ++jj) {
            float tv = s[jj * 16 + n];
            msq = fmaf(tv, tv, msq);
        }
        sc[n] = msq / ((1.f + msq) * sqrtf(fmaxf(msq, 1e-30f)));
    }
    __syncthreads();
    float vv = s[n] * sc[n & 15];
    vB[n * BB + b] = (u16)f2b(vv);
    if (write_out) out[b * 512 + n] = vv;
}

// ---------------------------------------------------------------------------
// gemmBf (fused): G[u][n][c] = sum_b vB[n][b] * xB[u][c][b] computed per-wave
// in registers; epilogue multiplies by Wn[n][c][u] (wave-uniform u), reduces
// over s (in-lane r + shfl over quad), atomicAdds (1/B)*sum into bb[j][c].
// 2048 blocks x 4 waves; wave = (u, 32n x 32c tile), K=128. No LDS.
__global__ __launch_bounds__(256) void k_gemmBf(const u16* __restrict__ vB,
                                                const u16* __restrict__ xB,
                                                const u16* __restrict__ Wn,
                                                float* __restrict__ bbp) {
    const bf16x8* A8 = (const bf16x8*)vB;
    const bf16x8* B8 = (const bf16x8*)xB;
    const uint4* Wn4 = (const uint4*)Wn;
    int t = threadIdx.x;
    int w = t >> 6, lane = t & 63;
    int gw = blockIdx.x * 4 + w;  // [0,8192)
    int u = gw >> 10, rest = gw & 1023;
    int nt = rest & 15, c0 = (rest >> 4) * 32;
    int n0 = nt * 32;
    int ln = lane & 15, quad = lane >> 4;
    bf16x8 av[2][4], bx[2][4];
#pragma unroll
    for (int mt = 0; mt < 2; ++mt)
#pragma unroll
        for (int st = 0; st < 4; ++st)
            av[mt][st] = A8[(n0 + mt * 16 + ln) * 16 + quad + 4 * st];
#pragma unroll
    for (int ct = 0; ct < 2; ++ct)
#pragma unroll
        for (int st = 0; st < 4; ++st)
            bx[ct][st] = B8[((size_t)u * CC + c0 + ct * 16 + ln) * 16 + quad + 4 * st];
    f32x4 acc[2][2];
    acc[0][0] = {0.f, 0.f, 0.f, 0.f};
    acc[0][1] = acc[0][0]; acc[1][0] = acc[0][0]; acc[1][1] = acc[0][0];
#pragma unroll
    for (int st = 0; st < 4; ++st)
#pragma unroll
        for (int mt = 0; mt < 2; ++mt)
#pragma unroll
            for (int ct = 0; ct < 2; ++ct)
                acc[mt][ct] = __builtin_amdgcn_mfma_f32_16x16x32_bf16(
                    av[mt][st], bx[ct][st], acc[mt][ct], 0, 0, 0);
    // Epilogue: lane holds G[n = n0+mt*16+quad*4+r][c = c0+ct*16+ln].
#pragma unroll
    for (int mt = 0; mt < 2; ++mt) {
        int j = 2 * nt + mt;
#pragma unroll
        for (int ct = 0; ct < 2; ++ct) {
            int c = c0 + ct * 16 + ln;
            float val = 0.f;
#pragma unroll
            for (int r = 0; r < 4; ++r) {
                int n = n0 + mt * 16 + quad * 4 + r;
                uint4 wp = Wn4[(size_t)n * 2048 + c];
                u32 warr[4] = {wp.x, wp.y, wp.z, wp.w};
                u32 ww = warr[u >> 1];
                float wv = (u & 1) ? bfhi(ww) : bflo(ww);
                val = fmaf(acc[mt][ct][r], wv, val);
            }
            val += __shfl_xor(val, 16, 64);
            val += __shfl_xor(val, 32, 64);
            if (quad == 0)
                atomicAdd(&bbp[j * CC + c], val * (1.0f / BB));
        }
    }
}

// ---------------------------------------------------------------------------
extern "C" void kernel_launch(void* const* d_in, const int* in_sizes, int n_in,
                              void* d_out, int out_size, void* d_ws, size_t ws_size,
                              hipStream_t stream) {
    const float* x = (const float*)d_in[0];
    const float* W = (const float*)d_in[1];
    if (in_sizes[0] == CC * JJ * SS * UU) {  // robustness: order by size
        x = (const float*)d_in[1];
        W = (const float*)d_in[0];
    }
    float* out = (float*)d_out;  // fp32 output

    char* ws = (char*)d_ws;
    float* spart = (float*)ws;                  // 32 MiB (128 slices)
    u16* xA = (u16*)(ws + (32u << 20));         // 4 MiB
    u16* xB = (u16*)(ws + (36u << 20));         // 4 MiB
    u16* Wn = (u16*)(ws + (40u << 20));         // 16 MiB
    size_t b64 = (size_t)64u << 20;
    u16* vB = (u16*)(ws + b64);                 // 128 KiB
    float* bbp = (float*)(ws + b64 + 131072);   // 256 KiB
    float* ccp = (float*)(ws + b64 + 393216);   // 256 KiB

    k_prep<<<2576, 256, 0, stream>>>(x, W, xA, xB, Wn, bbp);

    for (int it = 0; it < 3; ++it) {
        if (it > 0) k_softmax<<<32, 256, 0, stream>>>(bbp, ccp);
        k_gemmA<<<512, 256, 0, stream>>>(xA, Wn, ccp, it > 0 ? 1 : 0, spart);
        k_rsq<<<128, 512, 0, stream>>>(spart, vB, out,
                                       it == 0 ? (1.0f / 2048.0f) : 1.0f,
                                       it == 2 ? 1 : 0);
        if (it < 2) k_gemmBf<<<2048, 256, 0, stream>>>(vB, xB, Wn, bbp);
    }
}